// Round 1
// baseline (1519.235 us; speedup 1.0000x reference)
//
#include <hip/hip_runtime.h>

// SparseLinear: y = x @ W^T + bias, W scattered from COO (sum duplicates).
// Strategy: scatter to dense W (fp32 atomics) -> bf16, then dense bf16 MFMA GEMM
// (m97-style 128x128 tile, BK=32, global_load_lds width-16 staging).

#define M_DIM 65536
#define K_DIM 2048
#define N_DIM 2048
#define NNZ_CNT 262144

typedef short bf16x8 __attribute__((ext_vector_type(8)));
typedef float f32x4 __attribute__((ext_vector_type(4)));
typedef unsigned int u32x4 __attribute__((ext_vector_type(4)));

__device__ __forceinline__ unsigned short f2bf(float f) {
  union { float f; unsigned u; } v; v.f = f;
  unsigned r = v.u + 0x7fffu + ((v.u >> 16) & 1u);  // RNE
  return (unsigned short)(r >> 16);
}

__device__ __forceinline__ void glds16(const void* g, const void* l) {
  __builtin_amdgcn_global_load_lds(
      (const __attribute__((address_space(1))) void*)g,
      (__attribute__((address_space(3))) void*)l, 16, 0, 0);
}

__global__ void scatter_kernel(float* __restrict__ W, const float* __restrict__ vals,
                               const int* __restrict__ rows, const int* __restrict__ cols) {
  int i = blockIdx.x * 256 + threadIdx.x;
  atomicAdd(&W[(size_t)rows[i] * K_DIM + cols[i]], vals[i]);
}

// fp32 -> bf16, 8 elements/thread. total elements must be multiple of 2048.
__global__ void cvt_kernel(const float* __restrict__ in, unsigned short* __restrict__ out) {
  size_t i = ((size_t)blockIdx.x * 256 + threadIdx.x) * 8;
  f32x4 a = *(const f32x4*)(in + i);
  f32x4 b = *(const f32x4*)(in + i + 4);
  u32x4 p;
  p.x = f2bf(a.x) | ((unsigned)f2bf(a.y) << 16);
  p.y = f2bf(a.z) | ((unsigned)f2bf(a.w) << 16);
  p.z = f2bf(b.x) | ((unsigned)f2bf(b.y) << 16);
  p.w = f2bf(b.z) | ((unsigned)f2bf(b.w) << 16);
  *(u32x4*)(out + i) = p;
}

// C[m,n] = sum_k A[m,k] * W[n,k] + bias[n].
// PRECONV: A is pre-converted bf16 [M,K]; else A staged from fp32 with inline cvt.
template <bool PRECONV>
__global__ __launch_bounds__(256) void gemm_kernel(
    const float* __restrict__ xf, const unsigned short* __restrict__ xb,
    const unsigned short* __restrict__ wb, const float* __restrict__ bias,
    float* __restrict__ out) {
  __shared__ __align__(16) unsigned short lsA[128 * 32];
  __shared__ __align__(16) unsigned short lsB[128 * 32];
  const int tid = threadIdx.x;
  const int lane = tid & 63;
  const int wave = tid >> 6;
  const int m0 = blockIdx.y * 128;
  const int n0 = blockIdx.x * 128;
  const int r = lane & 15;   // MFMA row selector (m for A, n for B/D-col)
  const int q = lane >> 4;   // quad: k-group for A/B, row-group for D
  const int wm = (wave & 1) * 64;
  const int wn = (wave >> 1) * 64;

  f32x4 acc[4][4] = {};

  // global_load_lds staging geometry: dest byte = i*4096 + wave*1024 + lane*16
  const int srow = wave * 16 + (lane >> 2);  // + i*64
  const int scol = (lane & 3) * 8;           // element offset within 32-elem row

  for (int kt = 0; kt < K_DIM / 32; ++kt) {
    const int kb = kt * 32;
    if (PRECONV) {
#pragma unroll
      for (int i = 0; i < 2; ++i) {
        const unsigned short* g =
            xb + (size_t)(m0 + i * 64 + srow) * K_DIM + kb + scol;
        glds16(g, lsA + i * 2048 + wave * 512);
      }
    } else {
      const int row = tid >> 1;
      const int ce = (tid & 1) * 16;
      const float* g = xf + (size_t)(m0 + row) * K_DIM + kb + ce;
      f32x4 f0 = ((const f32x4*)g)[0];
      f32x4 f1 = ((const f32x4*)g)[1];
      f32x4 f2 = ((const f32x4*)g)[2];
      f32x4 f3 = ((const f32x4*)g)[3];
      u32x4 p0, p1;
      p0.x = f2bf(f0.x) | ((unsigned)f2bf(f0.y) << 16);
      p0.y = f2bf(f0.z) | ((unsigned)f2bf(f0.w) << 16);
      p0.z = f2bf(f1.x) | ((unsigned)f2bf(f1.y) << 16);
      p0.w = f2bf(f1.z) | ((unsigned)f2bf(f1.w) << 16);
      p1.x = f2bf(f2.x) | ((unsigned)f2bf(f2.y) << 16);
      p1.y = f2bf(f2.z) | ((unsigned)f2bf(f2.w) << 16);
      p1.z = f2bf(f3.x) | ((unsigned)f2bf(f3.y) << 16);
      p1.w = f2bf(f3.z) | ((unsigned)f2bf(f3.w) << 16);
      *(u32x4*)(lsA + row * 32 + ce) = p0;
      *(u32x4*)(lsA + row * 32 + ce + 8) = p1;
    }
#pragma unroll
    for (int i = 0; i < 2; ++i) {
      const unsigned short* g =
          wb + (size_t)(n0 + i * 64 + srow) * K_DIM + kb + scol;
      glds16(g, lsB + i * 2048 + wave * 512);
    }
    __syncthreads();  // drains vmcnt (global_load_lds) + lgkmcnt (ds_write)

    bf16x8 af[4], bfr[4];
#pragma unroll
    for (int mi = 0; mi < 4; ++mi)
      af[mi] = *(const bf16x8*)(lsA + (wm + mi * 16 + r) * 32 + q * 8);
#pragma unroll
    for (int ni = 0; ni < 4; ++ni)
      bfr[ni] = *(const bf16x8*)(lsB + (wn + ni * 16 + r) * 32 + q * 8);
#pragma unroll
    for (int mi = 0; mi < 4; ++mi)
#pragma unroll
      for (int ni = 0; ni < 4; ++ni)
        acc[mi][ni] = __builtin_amdgcn_mfma_f32_16x16x32_bf16(
            af[mi], bfr[ni], acc[mi][ni], 0, 0, 0);
    __syncthreads();
  }

  // epilogue: D layout col = lane&15 (=r), row = q*4 + reg
#pragma unroll
  for (int ni = 0; ni < 4; ++ni) {
    const int n = n0 + wn + ni * 16 + r;
    const float bv = bias[n];
#pragma unroll
    for (int mi = 0; mi < 4; ++mi) {
      const int mbase = m0 + wm + mi * 16 + q * 4;
#pragma unroll
      for (int reg = 0; reg < 4; ++reg)
        out[(size_t)(mbase + reg) * N_DIM + n] = acc[mi][ni][reg] + bv;
    }
  }
}

extern "C" void kernel_launch(void* const* d_in, const int* in_sizes, int n_in,
                              void* d_out, int out_size, void* d_ws, size_t ws_size,
                              hipStream_t stream) {
  const float* x = (const float*)d_in[0];
  const float* values = (const float*)d_in[1];
  const float* bias = (const float*)d_in[2];
  const int* rows = (const int*)d_in[3];
  const int* cols = (const int*)d_in[4];
  float* out = (float*)d_out;

  unsigned char* ws = (unsigned char*)d_ws;
  float* Wf = (float*)ws;                                    // 16 MB fp32 W
  unsigned short* Wb = (unsigned short*)(ws + (16u << 20));  // 8 MB bf16 W [N,K]
  unsigned short* Xb = (unsigned short*)(ws + (24u << 20));  // 256 MB bf16 x

  hipMemsetAsync(Wf, 0, (size_t)N_DIM * K_DIM * sizeof(float), stream);
  scatter_kernel<<<NNZ_CNT / 256, 256, 0, stream>>>(Wf, values, rows, cols);
  cvt_kernel<<<(N_DIM * K_DIM) / 2048, 256, 0, stream>>>(Wf, Wb);

  const size_t need = (24u << 20) + (size_t)M_DIM * K_DIM * 2;
  dim3 grid(N_DIM / 128, M_DIM / 128);  // x-fastest: 16 n-tiles share an x panel
  if (ws_size >= need) {
    cvt_kernel<<<((size_t)M_DIM * K_DIM) / 2048, 256, 0, stream>>>(x, Xb);
    gemm_kernel<true><<<grid, 256, 0, stream>>>(nullptr, Xb, Wb, bias, out);
  } else {
    gemm_kernel<false><<<grid, 256, 0, stream>>>(x, nullptr, Wb, bias, out);
  }
}